// Round 6
// baseline (317.621 us; speedup 1.0000x reference)
//
#include <hip/hip_runtime.h>
#include <math.h>

// ---------- types ----------
typedef __attribute__((ext_vector_type(8)))  short  short8;   // 8 bf16 (4 VGPRs) MFMA A/B frag
typedef __attribute__((ext_vector_type(16))) float  f32x16;   // 32x32 MFMA C/D frag
typedef __attribute__((ext_vector_type(4)))  float  float4v;
typedef __attribute__((ext_vector_type(8)))  unsigned short ushort8;
typedef __attribute__((ext_vector_type(4)))  unsigned short ushort4v;

#define NDIM 4096
#define BM 256
#define BN 256
#define BK 64

// fp32 -> bf16, round-to-nearest-even
__device__ __forceinline__ unsigned short f2bf(float f) {
  unsigned u = __builtin_bit_cast(unsigned, f);
  u += 0x7fffu + ((u >> 16) & 1u);
  return (unsigned short)(u >> 16);
}

// async global->LDS DMA, 16B/lane. LDS dest must be wave-uniform base + lane*16.
__device__ __forceinline__ void gload_lds16(const unsigned short* g, unsigned short* l) {
  __builtin_amdgcn_global_load_lds(
      (const __attribute__((address_space(1))) void*)g,
      (__attribute__((address_space(3))) void*)l, 16, 0, 0);
}

// ---------- fused prep: A fp32->bf16 (blocks 0..8191) ; W -> Wt bf16 (8192..12287) ----------
__global__ void prep(const float* __restrict__ A, unsigned short* __restrict__ Abf,
                     const float* __restrict__ W, unsigned short* __restrict__ Wt) {
  __shared__ unsigned short tileb[64][68];
  const int t = threadIdx.x;                 // 0..255
  if (blockIdx.x < 8192) {
    int i = (blockIdx.x * 256 + t) * 8;
    float4v a = *(const float4v*)(A + i);
    float4v b = *(const float4v*)(A + i + 4);
    ushort8 o;
    o[0] = f2bf(a[0]); o[1] = f2bf(a[1]); o[2] = f2bf(a[2]); o[3] = f2bf(a[3]);
    o[4] = f2bf(b[0]); o[5] = f2bf(b[1]); o[6] = f2bf(b[2]); o[7] = f2bf(b[3]);
    *(ushort8*)(Abf + i) = o;
  } else {
    int b  = blockIdx.x - 8192;
    int n0 = (b & 63) * 64, k0 = (b >> 6) * 64;
    const int rr = t >> 4;
    const int cc = (t & 15) * 4;
#pragma unroll
    for (int i = 0; i < 4; ++i) {
      int k = rr + i * 16;
      float4v v = *(const float4v*)&W[(size_t)(k0 + k) * NDIM + n0 + cc];
      ushort4v u;
      u[0] = f2bf(v[0]); u[1] = f2bf(v[1]); u[2] = f2bf(v[2]); u[3] = f2bf(v[3]);
      *(ushort4v*)&tileb[k][cc] = u;
    }
    __syncthreads();
#pragma unroll
    for (int i = 0; i < 2; ++i) {
      int c  = t + i * 256;
      int n  = c >> 3;
      int kc = (c & 7) * 8;
      ushort8 v;
#pragma unroll
      for (int j = 0; j < 8; ++j) v[j] = tileb[kc + j][n];
      *(ushort8*)&Wt[(size_t)(n0 + n) * NDIM + k0 + kc] = v;
    }
  }
}

// ---------- gemm: 256x256 block, wave tile 128x128, MFMA 32x32x16, XOR-8 swizzle,
// true double-buffered LDS (2x64KB), ONE barrier per K-iter, prefetch in flight
// across the whole compute phase (drained at the NEXT barrier). ----------
// R5 post-mortem: LDS-port floor (~91 us) + exposed per-iter DMA latency were the
// limit. Wave tile 128x128 halves LDS reads (intensity 64 FLOP/B, floor ~55 us =
// MFMA floor); dbuf+single-barrier hides DMA latency behind ~2000cy of MFMA.
// 1 wave/SIMD, 1 block/CU (grid 256) -- 16 independent acc chains keep MFMA fed.
__global__ __launch_bounds__(256, 1)
void gemm_bt_quant(const unsigned short* __restrict__ A,
                   const unsigned short* __restrict__ Bt,
                   const float* __restrict__ bias,
                   float* __restrict__ C) {
  __shared__ unsigned short As[2][BM * BK];   // 2 x 32 KB
  __shared__ unsigned short Bs[2][BN * BK];   // 2 x 32 KB  -> 128 KB total

  const int tid  = threadIdx.x;
  const int lane = tid & 63;
  const int wid  = tid >> 6;                // 4 waves, 2x2: wave tile 128x128
  const int wm   = (wid >> 1) * 128;
  const int wn   = (wid & 1) * 128;
  const int m0   = blockIdx.y * BM;
  const int n0   = blockIdx.x * BN;

  // staging: slot s = p*256+tid -> dest row s>>3 (= p*32 + tid>>3), dest chunk s&7;
  // source chunk = (s&7) ^ (row&7); row&7 == (tid>>3)&7 (rows advance 32/pass).
  const int srow = tid >> 3;                     // 0..31
  const int sc   = (tid & 7) ^ (srow & 7);       // swizzled source chunk
  const unsigned short* Ag = A  + (size_t)(m0 + srow) * NDIM + sc * 8;
  const unsigned short* Bg = Bt + (size_t)(n0 + srow) * NDIM + sc * 8;

  const int fr  = lane & 31;               // fragment row within 32-tile
  const int fh  = lane >> 5;               // K-half selector
  const int fsw = fr & 7;                  // read-side swizzle

  f32x16 acc[4][4] = {};

#define STAGE(buf, koff)                                                        \
  _Pragma("unroll")                                                             \
  for (int p = 0; p < 8; ++p) {                                                 \
    gload_lds16(Ag + (koff) + (size_t)(p * 32) * NDIM,                          \
                &As[buf][(p * 256 + tid) * 8]);                                 \
    gload_lds16(Bg + (koff) + (size_t)(p * 32) * NDIM,                          \
                &Bs[buf][(p * 256 + tid) * 8]);                                 \
  }

#define COMPUTE(buf)                                                            \
  _Pragma("unroll")                                                             \
  for (int h = 0; h < 4; ++h) {                                                 \
    const int cph = (2 * h + fh) ^ fsw;                                         \
    short8 af[4], bfr[4];                                                       \
    _Pragma("unroll")                                                           \
    for (int i = 0; i < 4; ++i)                                                 \
      af[i] = *(const short8*)&As[buf][(wm + i * 32 + fr) * BK + cph * 8];      \
    _Pragma("unroll")                                                           \
    for (int j = 0; j < 4; ++j)                                                 \
      bfr[j] = *(const short8*)&Bs[buf][(wn + j * 32 + fr) * BK + cph * 8];     \
    _Pragma("unroll")                                                           \
    for (int i = 0; i < 4; ++i)                                                 \
      _Pragma("unroll")                                                         \
      for (int j = 0; j < 4; ++j)                                               \
        acc[i][j] = __builtin_amdgcn_mfma_f32_32x32x16_bf16(af[i], bfr[j],      \
                                                            acc[i][j], 0, 0, 0);\
  }

  STAGE(0, 0);
  for (int kt = 0; kt < NDIM; kt += 2 * BK) {
    __syncthreads();                 // buf0 DMAs (per-wave vmcnt-drained) + all
                                     // waves done reading buf1 -> safe to refill
    STAGE(1, kt + BK);               // in flight across COMPUTE(0)
    COMPUTE(0);
    __syncthreads();
    int kn = kt + 2 * BK;
    if (kn >= NDIM) kn = 0;          // last prefetch: harmless dummy (branchless)
    STAGE(0, kn);
    COMPUTE(1);
  }
#undef STAGE
#undef COMPUTE

  // epilogue: fused quant + bias. C/D: col=lane&31, row=(reg&3)+8*(reg>>2)+4*fh.
  const float inv = 1.0f / 256.0f;
#pragma unroll
  for (int j = 0; j < 4; ++j) {
    const int col = n0 + wn + j * 32 + fr;
    const float qb = rintf(bias[col] * 256.0f) * inv;
#pragma unroll
    for (int i = 0; i < 4; ++i) {
      const int rb = m0 + wm + i * 32 + 4 * fh;
#pragma unroll
      for (int r = 0; r < 16; ++r) {
        const int row = rb + (r & 3) + 8 * (r >> 2);
        C[(size_t)row * NDIM + col] = rintf(acc[i][j][r] * 256.0f) * inv + qb;
      }
    }
  }
}

// ---------- fallback (ws too small): fp32 tiled GEMM, exact ----------
__global__ void gemm_fb(const float* __restrict__ A, const float* __restrict__ W,
                        const float* __restrict__ bias, float* __restrict__ C) {
  __shared__ float As[32][33], Ws[32][33];
  int tx = threadIdx.x, ty = threadIdx.y;     // (32,8)
  int m0 = blockIdx.y * 32, n0 = blockIdx.x * 32;
  float acc[4] = {0.f, 0.f, 0.f, 0.f};
  for (int k0 = 0; k0 < NDIM; k0 += 32) {
#pragma unroll
    for (int i = 0; i < 4; ++i) {
      int r = ty + i * 8;
      As[r][tx] = A[(size_t)(m0 + r) * NDIM + k0 + tx];
      Ws[r][tx] = W[(size_t)(k0 + r) * NDIM + n0 + tx];
    }
    __syncthreads();
#pragma unroll
    for (int k = 0; k < 32; ++k) {
      float wv = Ws[k][tx];
#pragma unroll
      for (int i = 0; i < 4; ++i) acc[i] += As[ty + i * 8][k] * wv;
    }
    __syncthreads();
  }
  float qb = rintf(bias[n0 + tx] * 256.0f) * (1.0f / 256.0f);
#pragma unroll
  for (int i = 0; i < 4; ++i)
    C[(size_t)(m0 + ty + i * 8) * NDIM + n0 + tx] =
        rintf(acc[i] * 256.0f) * (1.0f / 256.0f) + qb;
}

extern "C" void kernel_launch(void* const* d_in, const int* in_sizes, int n_in,
                              void* d_out, int out_size, void* d_ws, size_t ws_size,
                              hipStream_t stream) {
  const float* A    = (const float*)d_in[0];
  const float* W    = (const float*)d_in[1];
  const float* bias = (const float*)d_in[2];
  float* C = (float*)d_out;
  const size_t nElem = (size_t)NDIM * NDIM;

  if (ws_size >= nElem * 4) {   // need 2 bf16 matrices = 64 MB
    unsigned short* Abf = (unsigned short*)d_ws;
    unsigned short* Wt  = Abf + nElem;
    prep<<<8192 + 4096, 256, 0, stream>>>(A, Abf, W, Wt);
    gemm_bt_quant<<<dim3(NDIM / BN, NDIM / BM), 256, 0, stream>>>(Abf, Wt, bias, C);
  } else {
    gemm_fb<<<dim3(128, 128), dim3(32, 8), 0, stream>>>(A, W, bias, C);
  }
}

// Round 7
// 314.335 us; speedup vs baseline: 1.0105x; 1.0105x over previous
//
#include <hip/hip_runtime.h>
#include <math.h>

// ---------- types ----------
typedef __attribute__((ext_vector_type(8)))  short  short8;   // 8 bf16 (4 VGPRs) MFMA A/B frag
typedef __attribute__((ext_vector_type(16))) float  f32x16;   // 32x32 MFMA C/D frag
typedef __attribute__((ext_vector_type(4)))  float  float4v;
typedef __attribute__((ext_vector_type(8)))  unsigned short ushort8;
typedef __attribute__((ext_vector_type(4)))  unsigned short ushort4v;

#define NDIM 4096
#define BM 256
#define BN 128
#define BK 32

// fp32 -> bf16, round-to-nearest-even
__device__ __forceinline__ unsigned short f2bf(float f) {
  unsigned u = __builtin_bit_cast(unsigned, f);
  u += 0x7fffu + ((u >> 16) & 1u);
  return (unsigned short)(u >> 16);
}

// async global->LDS DMA, 16B/lane. LDS dest must be wave-uniform base + lane*16.
__device__ __forceinline__ void gload_lds16(const unsigned short* g, unsigned short* l) {
  __builtin_amdgcn_global_load_lds(
      (const __attribute__((address_space(1))) void*)g,
      (__attribute__((address_space(3))) void*)l, 16, 0, 0);
}

// ---------- fused prep: A fp32->bf16 (blocks 0..8191) ; W -> Wt bf16 (8192..12287) ----------
__global__ void prep(const float* __restrict__ A, unsigned short* __restrict__ Abf,
                     const float* __restrict__ W, unsigned short* __restrict__ Wt) {
  __shared__ unsigned short tileb[64][68];
  const int t = threadIdx.x;                 // 0..255
  if (blockIdx.x < 8192) {
    int i = (blockIdx.x * 256 + t) * 8;
    float4v a = *(const float4v*)(A + i);
    float4v b = *(const float4v*)(A + i + 4);
    ushort8 o;
    o[0] = f2bf(a[0]); o[1] = f2bf(a[1]); o[2] = f2bf(a[2]); o[3] = f2bf(a[3]);
    o[4] = f2bf(b[0]); o[5] = f2bf(b[1]); o[6] = f2bf(b[2]); o[7] = f2bf(b[3]);
    *(ushort8*)(Abf + i) = o;
  } else {
    int b  = blockIdx.x - 8192;
    int n0 = (b & 63) * 64, k0 = (b >> 6) * 64;
    const int rr = t >> 4;
    const int cc = (t & 15) * 4;
#pragma unroll
    for (int i = 0; i < 4; ++i) {
      int k = rr + i * 16;
      float4v v = *(const float4v*)&W[(size_t)(k0 + k) * NDIM + n0 + cc];
      ushort4v u;
      u[0] = f2bf(v[0]); u[1] = f2bf(v[1]); u[2] = f2bf(v[2]); u[3] = f2bf(v[3]);
      *(ushort4v*)&tileb[k][cc] = u;
    }
    __syncthreads();
#pragma unroll
    for (int i = 0; i < 2; ++i) {
      int c  = t + i * 256;
      int n  = c >> 3;
      int kc = (c & 7) * 8;
      ushort8 v;
#pragma unroll
      for (int j = 0; j < 8; ++j) v[j] = tileb[kc + j][n];
      *(ushort8*)&Wt[(size_t)(n0 + n) * NDIM + k0 + kc] = v;
    }
  }
}

// ---------- gemm: R5 tiling (256x128 block, wave 128x64, no spill: acc=128 regs)
// + R6 single-barrier double-buffer at BK=32 (2x24KB buffers, 48KB LDS total,
// 2 blocks/CU preserved). Every DMA stays in flight across a full COMPUTE phase
// (drained at the NEXT barrier) -> exposed per-iter load latency removed.
// XOR-4 swizzle: chunk c (16B) of row r stored at c^(r&3); applied on DMA
// SOURCE address (dest stays lane-linear), undone at fragment read. Worst
// residual aliasing is 2-way = free (m136).
__global__ __launch_bounds__(256, 2)
void gemm_bt_quant(const unsigned short* __restrict__ A,
                   const unsigned short* __restrict__ Bt,
                   const float* __restrict__ bias,
                   float* __restrict__ C) {
  __shared__ unsigned short As[2][BM * BK];   // 2 x 16 KB
  __shared__ unsigned short Bs[2][BN * BK];   // 2 x  8 KB

  const int tid  = threadIdx.x;
  const int lane = tid & 63;
  const int wid  = tid >> 6;                // 4 waves, 2x2: wave tile 128x64
  const int wm   = (wid >> 1) * 128;
  const int wn   = (wid & 1) * 64;
  const int m0   = blockIdx.y * BM;
  const int n0   = blockIdx.x * BN;

  // staging: slot s = p*256+tid -> dest row s>>2 (= p*64 + tid>>2), dest chunk s&3.
  // source logical chunk = (s&3) ^ (row&3); row&3 == (tid>>2)&3 (rows advance 64/pass).
  const int srow = tid >> 2;                     // 0..63
  const int sc   = (tid & 3) ^ (srow & 3);       // swizzled source chunk
  const unsigned short* Ag = A  + (size_t)(m0 + srow) * NDIM + sc * 8;
  const unsigned short* Bg = Bt + (size_t)(n0 + srow) * NDIM + sc * 8;

  const int fr  = lane & 31;               // fragment row within 32-tile
  const int fh  = lane >> 5;               // K-half selector
  const int fsw = fr & 3;                  // read-side swizzle (row&3)

  f32x16 acc[4][2] = {};

#define STAGE(buf, koff)                                                        \
  _Pragma("unroll")                                                             \
  for (int p = 0; p < 4; ++p)                                                   \
    gload_lds16(Ag + (koff) + (size_t)(p * 64) * NDIM,                          \
                &As[buf][(p * 256 + tid) * 8]);                                 \
  _Pragma("unroll")                                                             \
  for (int p = 0; p < 2; ++p)                                                   \
    gload_lds16(Bg + (koff) + (size_t)(p * 64) * NDIM,                          \
                &Bs[buf][(p * 256 + tid) * 8]);

#define COMPUTE(buf)                                                            \
  _Pragma("unroll")                                                             \
  for (int h = 0; h < 2; ++h) {                                                 \
    const int cph = (2 * h + fh) ^ fsw;                                         \
    short8 af[4], bfr[2];                                                       \
    _Pragma("unroll")                                                           \
    for (int i = 0; i < 4; ++i)                                                 \
      af[i] = *(const short8*)&As[buf][(wm + i * 32 + fr) * BK + cph * 8];      \
    _Pragma("unroll")                                                           \
    for (int j = 0; j < 2; ++j)                                                 \
      bfr[j] = *(const short8*)&Bs[buf][(wn + j * 32 + fr) * BK + cph * 8];     \
    _Pragma("unroll")                                                           \
    for (int i = 0; i < 4; ++i)                                                 \
      _Pragma("unroll")                                                         \
      for (int j = 0; j < 2; ++j)                                               \
        acc[i][j] = __builtin_amdgcn_mfma_f32_32x32x16_bf16(af[i], bfr[j],      \
                                                            acc[i][j], 0, 0, 0);\
  }

  STAGE(0, 0);
  for (int kt = 0; kt < NDIM; kt += 2 * BK) {
    __syncthreads();                 // buf0 DMAs complete (per-wave vmcnt drain
                                     // + barrier) & all waves done reading buf1
    STAGE(1, kt + BK);               // in flight across COMPUTE(0)
    COMPUTE(0);
    __syncthreads();
    int kn = kt + 2 * BK;
    if (kn >= NDIM) kn = 0;          // last prefetch: harmless dummy (uniform)
    STAGE(0, kn);
    COMPUTE(1);
  }
#undef STAGE
#undef COMPUTE

  // epilogue: fused quant + bias. C/D: col=lane&31, row=(reg&3)+8*(reg>>2)+4*fh.
  const float inv = 1.0f / 256.0f;
#pragma unroll
  for (int j = 0; j < 2; ++j) {
    const int col = n0 + wn + j * 32 + fr;
    const float qb = rintf(bias[col] * 256.0f) * inv;
#pragma unroll
    for (int i = 0; i < 4; ++i) {
      const int rb = m0 + wm + i * 32 + 4 * fh;
#pragma unroll
      for (int r = 0; r < 16; ++r) {
        const int row = rb + (r & 3) + 8 * (r >> 2);
        C[(size_t)row * NDIM + col] = rintf(acc[i][j][r] * 256.0f) * inv + qb;
      }
    }
  }
}

// ---------- fallback (ws too small): fp32 tiled GEMM, exact ----------
__global__ void gemm_fb(const float* __restrict__ A, const float* __restrict__ W,
                        const float* __restrict__ bias, float* __restrict__ C) {
  __shared__ float As[32][33], Ws[32][33];
  int tx = threadIdx.x, ty = threadIdx.y;     // (32,8)
  int m0 = blockIdx.y * 32, n0 = blockIdx.x * 32;
  float acc[4] = {0.f, 0.f, 0.f, 0.f};
  for (int k0 = 0; k0 < NDIM; k0 += 32) {
#pragma unroll
    for (int i = 0; i < 4; ++i) {
      int r = ty + i * 8;
      As[r][tx] = A[(size_t)(m0 + r) * NDIM + k0 + tx];
      Ws[r][tx] = W[(size_t)(k0 + r) * NDIM + n0 + tx];
    }
    __syncthreads();
#pragma unroll
    for (int k = 0; k < 32; ++k) {
      float wv = Ws[k][tx];
#pragma unroll
      for (int i = 0; i < 4; ++i) acc[i] += As[ty + i * 8][k] * wv;
    }
    __syncthreads();
  }
  float qb = rintf(bias[n0 + tx] * 256.0f) * (1.0f / 256.0f);
#pragma unroll
  for (int i = 0; i < 4; ++i)
    C[(size_t)(m0 + ty + i * 8) * NDIM + n0 + tx] =
        rintf(acc[i] * 256.0f) * (1.0f / 256.0f) + qb;
}

extern "C" void kernel_launch(void* const* d_in, const int* in_sizes, int n_in,
                              void* d_out, int out_size, void* d_ws, size_t ws_size,
                              hipStream_t stream) {
  const float* A    = (const float*)d_in[0];
  const float* W    = (const float*)d_in[1];
  const float* bias = (const float*)d_in[2];
  float* C = (float*)d_out;
  const size_t nElem = (size_t)NDIM * NDIM;

  if (ws_size >= nElem * 4) {   // need 2 bf16 matrices = 64 MB
    unsigned short* Abf = (unsigned short*)d_ws;
    unsigned short* Wt  = Abf + nElem;
    prep<<<8192 + 4096, 256, 0, stream>>>(A, Abf, W, Wt);
    gemm_bt_quant<<<dim3(NDIM / BN, NDIM / BM), 256, 0, stream>>>(Abf, Wt, bias, C);
  } else {
    gemm_fb<<<dim3(128, 128), dim3(32, 8), 0, stream>>>(A, W, bias, C);
  }
}